// Round 6
// baseline (1459.299 us; speedup 1.0000x reference)
//
#include <hip/hip_runtime.h>
#include <math.h>
#include <stdint.h>

// Problem constants
#define B_   256
#define T_   128
#define NIN_ 1024
#define H1_  512
#define E_   256
#define A_   16
#define MT_  (B_ * T_)   // 32768 rows, t-major: m = t*B_ + b

typedef unsigned short ushort_t;
typedef __attribute__((ext_vector_type(8))) short   short8;
typedef __attribute__((ext_vector_type(8))) __bf16  bf16x8;
typedef __attribute__((ext_vector_type(4))) float   f32x4;

union frag8 { short8 s; bf16x8 b; };

__device__ __forceinline__ ushort_t f2bf(float f) {
  union { float f; unsigned u; } v; v.f = f;
  unsigned r = (v.u + 0x7FFFu + ((v.u >> 16) & 1u)) >> 16;   // RNE
  return (ushort_t)r;
}

// ---------------- workspace layout (bytes) ----------------
// C0 fp32 [T*B][1024] = 128MB at 0 (written late; obs_b bf16 64MB overlays it early)
// chunks of C0 row: [0:256)=Penc(h_enc init) [256:512)=r_pre0 [512:768)=z_pre0 [768:1024)=hn0
static constexpr size_t OFF_C0    = 0;
static constexpr size_t OFF_OBSB  = 0;                      // bf16 [32768][1024], dead after G1
static constexpr size_t OFF_Y     = 134217728;              // fp32 [32768][512] (Y1,Y2)
static constexpr size_t OFF_YG    = 134217728;              // fp32 [32768][256] (after Y2 dead)
static constexpr size_t OFF_XG    = 167772160;              // bf16 [32768][256]
static constexpr size_t OFF_PENCB = 184549376;              // bf16 [32768][256] (after BN2)
static constexpr size_t OFF_XB    = 201326592;              // bf16 [32768][512] (X1,X2)
static constexpr size_t OFF_INN   = 201326592;              // fp32 [32768][256] (after XB dead)
static constexpr size_t OFF_AE    = 234881024;              // fp32 [32768][16]
static constexpr size_t OFF_W1T   = 236978176;              // bf16 [512][1024]
static constexpr size_t OFF_W2T   = 238026752;              // bf16 [512][512]
static constexpr size_t OFF_W3T   = 238551040;              // bf16 [256][512]
static constexpr size_t OFF_WIHT  = 239075328;              // bf16 [768][256]
static constexpr size_t OFF_WHHT  = 239468544;              // bf16 [768][256]
static constexpr size_t OFF_WCT   = 240123904;              // bf16 [1024][256]  (combined W^T)
static constexpr size_t OFF_BSUM  = 241172480;              // fp32 [768]

// ---------------- prologue kernels ----------------

// obs [B,T,NIN] fp32 -> obs_b bf16 t-major [t*B+b][NIN]
__global__ __launch_bounds__(256) void cast_obs_k(const float* __restrict__ obs,
                                                  ushort_t* __restrict__ out) {
  int row_in = blockIdx.x;              // b*T + t
  int b = row_in / T_, t = row_in - b * T_;
  const float4* s4 = (const float4*)(obs + (size_t)row_in * NIN_);
  float4 v = s4[threadIdx.x];
  ushort_t* d = out + (size_t)(t * B_ + b) * NIN_ + threadIdx.x * 4;
  d[0] = f2bf(v.x); d[1] = f2bf(v.y); d[2] = f2bf(v.z); d[3] = f2bf(v.w);
}

// generic fp32 [R,C] -> bf16 [C,R] transpose+cast
__global__ __launch_bounds__(256) void transpose_cast_k(const float* __restrict__ in,
                                                        ushort_t* __restrict__ out,
                                                        int R, int C) {
  __shared__ float tile[32][33];
  int c0 = blockIdx.x * 32, r0 = blockIdx.y * 32;
  int tx = threadIdx.x & 31, ty = threadIdx.x >> 5;   // ty 0..7
  for (int i = 0; i < 4; i++) {
    int r = r0 + ty * 4 + i;
    if (r < R && (c0 + tx) < C) tile[ty * 4 + i][tx] = in[(size_t)r * C + c0 + tx];
  }
  __syncthreads();
  for (int i = 0; i < 4; i++) {
    int c = c0 + ty * 4 + i, r = r0 + tx;
    if (c < C && r < R) out[(size_t)c * R + r] = f2bf(tile[tx][ty * 4 + i]);
  }
}

// Wct rows 0..255: (Whe_h)^T  : Wct[c][k] = Whe[k][c]
__global__ __launch_bounds__(256) void wct_a_k(const float* __restrict__ Whe,
                                               ushort_t* __restrict__ Wct) {
  int c = blockIdx.x, k = threadIdx.x;
  Wct[(size_t)c * 256 + k] = f2bf(Whe[(size_t)k * 256 + c]);
}

// Wct rows 256..1023: (Whe_h @ Whh)^T computed in fp32, one bf16 rounding
__global__ __launch_bounds__(256) void wct_b_k(const float* __restrict__ Whe,
                                               const float* __restrict__ Whh,
                                               ushort_t* __restrict__ Wct) {
  int c = blockIdx.x;   // 0..767 (gh column)
  int k = threadIdx.x;  // h feature
  float acc = 0.f;
  for (int j = 0; j < 256; j++)
    acc += Whe[(size_t)k * 256 + j] * Whh[(size_t)j * 768 + c];
  Wct[(size_t)(256 + c) * 256 + k] = f2bf(acc);
}

__global__ void bsum_k(const float* __restrict__ bih, const float* __restrict__ bhh,
                       float* __restrict__ bs) {
  int i = blockIdx.x * 256 + threadIdx.x;
  if (i < 768) bs[i] = bih[i] + bhh[i];
}

// AE[m=t*B+b][k2] = actions[b,t,:] @ Wae + bae   (fp32)
__global__ __launch_bounds__(256) void ae_k(const float* __restrict__ actions,
                                            const float* __restrict__ Wae,
                                            const float* __restrict__ bae,
                                            float* __restrict__ AE) {
  int idx = blockIdx.x * 256 + threadIdx.x;
  int m = idx >> 4, k2 = idx & 15;
  int t = m >> 8, b = m & 255;
  const float* arow = actions + ((size_t)b * T_ + t) * A_;
  float acc = bae[k2];
  for (int k = 0; k < 16; k++) acc += arow[k] * Wae[k * 16 + k2];
  AE[(size_t)m * 16 + k2] = acc;
}

// Penc[t][b][j] = bhe[j] + (t>0 ? AE[t-1,b,:] @ Whe[256:272,:] : 0)
// writes fp32 into C0 cols [0:256) and bf16 copy to Pencb
__global__ __launch_bounds__(256) void penc_k(const float* __restrict__ AE,
                                              const float* __restrict__ Whe,
                                              const float* __restrict__ bhe,
                                              float* __restrict__ C0,
                                              ushort_t* __restrict__ Pencb) {
  int m = blockIdx.x;          // t*B + b
  int j = threadIdx.x;         // 0..255
  __shared__ float a[16];
  if (threadIdx.x < 16)
    a[threadIdx.x] = (m >= B_) ? AE[(size_t)(m - B_) * 16 + threadIdx.x] : 0.f;
  __syncthreads();
  float acc = bhe[j];
  if (m >= B_) {
    for (int k = 0; k < 16; k++) acc += a[k] * Whe[(size_t)(256 + k) * 256 + j];
  }
  C0[(size_t)m * 1024 + j] = acc;
  Pencb[(size_t)m * 256 + j] = f2bf(acc);
}

// per-t BatchNorm (training, biased var) + ELU, fp32 in -> bf16 out
__global__ __launch_bounds__(512) void bn_elu_k(const float* __restrict__ Y,
                                                const float* __restrict__ g,
                                                const float* __restrict__ be,
                                                ushort_t* __restrict__ Xb) {
  int t = blockIdx.x, f = threadIdx.x;   // 512 features
  const float* base = Y + (size_t)t * B_ * H1_;
  float s = 0.f, ss = 0.f;
  for (int b = 0; b < B_; b++) {
    float v = base[(size_t)b * H1_ + f];
    s += v; ss += v * v;
  }
  float mu  = s * (1.f / B_);
  float var = ss * (1.f / B_) - mu * mu;
  float inv = 1.f / sqrtf(var + 1e-5f);
  float sc = g[f] * inv, sh = be[f] - mu * sc;
  ushort_t* ob = Xb + (size_t)t * B_ * H1_;
  for (int b = 0; b < B_; b++) {
    float v = base[(size_t)b * H1_ + f] * sc + sh;
    float e = v > 0.f ? v : (expf(v) - 1.f);
    ob[(size_t)b * H1_ + f] = f2bf(e);
  }
}

__global__ __launch_bounds__(256) void cast_k(const float* __restrict__ in,
                                              ushort_t* __restrict__ out, long n) {
  long i = (long)blockIdx.x * 256 + threadIdx.x;
  if (i < n) out[i] = f2bf(in[i]);
}

// ---------------- bf16 MFMA GEMM: C[m,n] (+)= A[m,:] . Bt[n,:] + bias[n] ----------------
// A: bf16 [M,lda], Bt: bf16 [N,ldb] (B transposed), C: fp32 (ldc).
// v5: 128x128 tile (m93-style), BK=32, 256 threads (4 waves in 2x2, each 64x64,
// 4x4 fragment grid). LDS padded +8 -> 2-way bank aliasing only (free).
// grid = (M/128, N/128).
__global__ __launch_bounds__(256) void gemm_bt_k(const ushort_t* __restrict__ A, int lda,
                                                 const ushort_t* __restrict__ Bt, int ldb,
                                                 float* __restrict__ C, int ldc,
                                                 const float* __restrict__ bias,
                                                 int K, int accum) {
  __shared__ __align__(16) ushort_t As[128][40];
  __shared__ __align__(16) ushort_t Bs[128][40];
  int tid = threadIdx.x;
  int wave = tid >> 6, lane = tid & 63;
  int q = lane >> 4, l15 = lane & 15;
  int wr = wave >> 1, wc = wave & 1;
  int m0 = blockIdx.x * 128, n0 = blockIdx.y * 128;
  f32x4 acc[4][4] = {};
  int r = tid >> 1, sh = (tid & 1) * 16;     // each thread stages 2x 8-elem segs per matrix
  const ushort_t* aSrc = A + (size_t)(m0 + r) * lda + sh;
  const ushort_t* bSrc = Bt + (size_t)(n0 + r) * ldb + sh;
  for (int k0 = 0; k0 < K; k0 += 32) {
    *(short8*)&As[r][sh]     = *(const short8*)(aSrc + k0);
    *(short8*)&As[r][sh + 8] = *(const short8*)(aSrc + k0 + 8);
    *(short8*)&Bs[r][sh]     = *(const short8*)(bSrc + k0);
    *(short8*)&Bs[r][sh + 8] = *(const short8*)(bSrc + k0 + 8);
    __syncthreads();
    frag8 af[4], bf[4];
#pragma unroll
    for (int i = 0; i < 4; i++) {
      af[i].s = *(const short8*)&As[wr * 64 + i * 16 + l15][q * 8];
      bf[i].s = *(const short8*)&Bs[wc * 64 + i * 16 + l15][q * 8];
    }
#pragma unroll
    for (int at = 0; at < 4; at++)
#pragma unroll
      for (int bt = 0; bt < 4; bt++)
        acc[at][bt] = __builtin_amdgcn_mfma_f32_16x16x32_bf16(af[at].b, bf[bt].b, acc[at][bt], 0, 0, 0);
    __syncthreads();
  }
#pragma unroll
  for (int at = 0; at < 4; at++)
#pragma unroll
    for (int bt = 0; bt < 4; bt++) {
      int mb = m0 + wr * 64 + at * 16 + q * 4;       // C/D: row = quad*4+i
      int n  = n0 + wc * 64 + bt * 16 + l15;         //      col = lane&15
      float bv = bias ? bias[n] : 0.f;
#pragma unroll
      for (int i = 0; i < 4; i++) {
        size_t idx = (size_t)(mb + i) * ldc + n;
        float v = acc[at][bt][i] + bv;
        if (accum) v += C[idx];
        C[idx] = v;
      }
    }
}

// ---------------- communication-free GRU recurrence (v5) ----------------
// Row partition: block k owns batch rows [16k,16k+16) for ALL 128 steps; no
// inter-block communication. 1024 thr = 16 waves (4/SIMD). Wave w owns h-cols
// [16w,16w+16), all 4 gates in-lane.
// v4 post-mortem: 2x TLP changed nothing -> throughput-bound on per-CU load
// path; VGPR=64 showed allocator demoted even 32-VGPR stationary weights.
// v5 fix: henc AND r weights stationary (64 VGPR) with asm keep-alive chained
// through the t-loop -- the "+v" output must be carried iteration-to-iteration,
// making per-step rematerialization from global illegal.
// Residency plan: hn weights LDS (135KB); henc+r VGPR (64); z streamed (128KB
// per step, L2-hit); C0/INN (80KB, L3-hit) prefetched at step top.
// VGPR budget: 64 wts + 16 acc + 20 prefetch + ~20 frags/addr ~= 120 < 128 cap.
// Stream floor: 208KB/step / ~64B/cy ~= 3300cy ~= 1.4us/step.
__global__ __launch_bounds__(1024, 4) void gru_rows_k(
    const ushort_t* __restrict__ Wct,
    const float* __restrict__ C0,
    const float* __restrict__ INN,
    float* __restrict__ outF) {
  __shared__ __align__(16) ushort_t Wn[256][264];       // hn weights (135KB)
  __shared__ __align__(16) ushort_t hbuf[2][16][264];   // h double-buffer (17KB)
  const int tid = threadIdx.x;
  const int w = tid >> 6, lane = tid & 63;
  const int q = lane >> 4, l15 = lane & 15;
  const int r0 = blockIdx.x * 16;          // batch rows [r0, r0+16)
  const int col0 = w * 16;                 // wave's h-col base (16 cols)

  // zero h(0) (both buffers, incl. pad)
  {
    unsigned* hz = (unsigned*)hbuf;
    for (int i = tid; i < 2 * 16 * 264 / 2; i += 1024) hz[i] = 0u;
  }
  // stage hn weights (Wct rows 768..1023) into LDS
  for (int i = tid; i < 256 * 32; i += 1024) {
    int rr = i >> 5, ss = i & 31;
    *(short8*)&Wn[rr][ss * 8] = *(const short8*)(Wct + (size_t)(768 + rr) * 256 + ss * 8);
  }

  // VGPR-stationary henc (rows 0..255) and r (rows 256..511) weights: 64 VGPR
  frag8 whe_s[8], wr_s[8];
  {
    const ushort_t* p0 = Wct + (size_t)(col0 + l15) * 256 + q * 8;
    const ushort_t* p1 = Wct + (size_t)(256 + col0 + l15) * 256 + q * 8;
#pragma unroll
    for (int kc = 0; kc < 8; kc++) {
      whe_s[kc].s = *(const short8*)(p0 + kc * 32);
      wr_s[kc].s  = *(const short8*)(p1 + kc * 32);
    }
  }
  // streamed base: z (rows 512+)
  const ushort_t* wz_ = Wct + (size_t)(512 + col0 + l15) * 256 + q * 8;

  __syncthreads();

  const int hc = col0 + l15;               // this lane's h-col

  for (int t = 0; t < T_; t++) {
    // keep-alive: chain stationary weights through the loop so the allocator
    // cannot demote them to per-step global reloads (v3/v4 failure mode).
#pragma unroll
    for (int kc = 0; kc < 8; kc++) {
      asm volatile("" : "+v"(whe_s[kc].s));
      asm volatile("" : "+v"(wr_s[kc].s));
    }

    const int cur = t & 1, nxt = cur ^ 1;
    const float* c0t  = C0  + ((size_t)t * B_ + r0) * 1024;
    const float* innt = INN + ((size_t)t * B_ + r0) * 256;

    // prefetch ALL per-step C0/INN (20 dwords/lane), consumed in epilogue
    float c0g[4][4], innv[4];
#pragma unroll
    for (int i = 0; i < 4; i++) {
      int row = q * 4 + i;
      const float* rp = c0t + (size_t)row * 1024 + hc;
      c0g[0][i] = rp[0];
      c0g[1][i] = rp[256];
      c0g[2][i] = rp[512];
      c0g[3][i] = rp[768];
      innv[i] = innt[(size_t)row * 256 + hc];
    }

    f32x4 acc[4] = {};   // [gate]
#pragma unroll
    for (int kc = 0; kc < 8; kc++) {
      frag8 a; a.s = *(const short8*)&hbuf[cur][l15][kc * 32 + q * 8];
      frag8 bz_, bn_;
      bz_.s = *(const short8*)(wz_ + kc * 32);
      bn_.s = *(const short8*)&Wn[hc][kc * 32 + q * 8];
      acc[0] = __builtin_amdgcn_mfma_f32_16x16x32_bf16(a.b, whe_s[kc].b, acc[0], 0, 0, 0);
      acc[1] = __builtin_amdgcn_mfma_f32_16x16x32_bf16(a.b, wr_s[kc].b, acc[1], 0, 0, 0);
      acc[2] = __builtin_amdgcn_mfma_f32_16x16x32_bf16(a.b, bz_.b, acc[2], 0, 0, 0);
      acc[3] = __builtin_amdgcn_mfma_f32_16x16x32_bf16(a.b, bn_.b, acc[3], 0, 0, 0);
    }

    // epilogue: gate math on prefetched values, write h(t+1) to LDS
#pragma unroll
    for (int i = 0; i < 4; i++) {
      int row = q * 4 + i;
      float henc = acc[0][i] + c0g[0][i];
      float rp   = acc[1][i] + c0g[1][i];
      float zp   = acc[2][i] + c0g[2][i];
      float hn   = acc[3][i] + c0g[3][i];
      float rg = 1.f / (1.f + expf(-rp));
      float zg = 1.f / (1.f + expf(-zp));
      float ng = tanhf(innv[i] + rg * hn);
      float hv = (1.f - zg) * ng + zg * henc;
      if (t < T_ - 1) hbuf[nxt][row][hc] = f2bf(hv);
      else            outF[(size_t)(r0 + row) * 256 + hc] = hv;
    }
    __syncthreads();   // h(t+1) complete before any wave reads it next step
  }
}

// ---------------- launch ----------------
extern "C" void kernel_launch(void* const* d_in, const int* in_sizes, int n_in,
                              void* d_out, int out_size, void* d_ws, size_t ws_size,
                              hipStream_t stream) {
  const float* obs     = (const float*)d_in[0];
  const float* actions = (const float*)d_in[1];
  const float* W1  = (const float*)d_in[2];
  const float* b1  = (const float*)d_in[3];
  const float* g1  = (const float*)d_in[4];
  const float* be1 = (const float*)d_in[5];
  const float* W2  = (const float*)d_in[6];
  const float* b2  = (const float*)d_in[7];
  const float* g2  = (const float*)d_in[8];
  const float* be2 = (const float*)d_in[9];
  const float* W3  = (const float*)d_in[10];
  const float* b3  = (const float*)d_in[11];
  const float* Wih = (const float*)d_in[12];
  const float* bih = (const float*)d_in[13];
  const float* Whh = (const float*)d_in[14];
  const float* bhh = (const float*)d_in[15];
  const float* Whe = (const float*)d_in[16];
  const float* bhe = (const float*)d_in[17];
  const float* Wae = (const float*)d_in[18];
  const float* bae = (const float*)d_in[19];

  char* ws = (char*)d_ws;
  float*    C0    = (float*)(ws + OFF_C0);
  ushort_t* obsb  = (ushort_t*)(ws + OFF_OBSB);
  float*    Y     = (float*)(ws + OFF_Y);
  float*    Yg    = (float*)(ws + OFF_YG);
  ushort_t* XG    = (ushort_t*)(ws + OFF_XG);
  ushort_t* Pencb = (ushort_t*)(ws + OFF_PENCB);
  ushort_t* Xb    = (ushort_t*)(ws + OFF_XB);
  float*    INN   = (float*)(ws + OFF_INN);
  float*    AE    = (float*)(ws + OFF_AE);
  ushort_t* W1t   = (ushort_t*)(ws + OFF_W1T);
  ushort_t* W2t   = (ushort_t*)(ws + OFF_W2T);
  ushort_t* W3t   = (ushort_t*)(ws + OFF_W3T);
  ushort_t* Wiht  = (ushort_t*)(ws + OFF_WIHT);
  ushort_t* Whht  = (ushort_t*)(ws + OFF_WHHT);
  ushort_t* Wct   = (ushort_t*)(ws + OFF_WCT);
  float*    bsum  = (float*)(ws + OFF_BSUM);
  float*    outF  = (float*)d_out;

  // prologue: casts / transposes / small precomputes
  cast_obs_k<<<MT_, 256, 0, stream>>>(obs, obsb);
  transpose_cast_k<<<dim3(16, 32), 256, 0, stream>>>(W1, W1t, 1024, 512);
  transpose_cast_k<<<dim3(16, 16), 256, 0, stream>>>(W2, W2t, 512, 512);
  transpose_cast_k<<<dim3(8, 16),  256, 0, stream>>>(W3, W3t, 512, 256);
  transpose_cast_k<<<dim3(24, 8),  256, 0, stream>>>(Wih, Wiht, 256, 768);
  transpose_cast_k<<<dim3(24, 8),  256, 0, stream>>>(Whh, Whht, 256, 768);
  wct_a_k<<<256, 256, 0, stream>>>(Whe, Wct);
  wct_b_k<<<768, 256, 0, stream>>>(Whe, Whh, Wct);
  bsum_k<<<3, 256, 0, stream>>>(bih, bhh, bsum);
  ae_k<<<MT_ * 16 / 256, 256, 0, stream>>>(actions, Wae, bae, AE);

  // MLP (parallel over all T*B rows, t-major) -- 128x128 tiles now
  gemm_bt_k<<<dim3(256, 4), 256, 0, stream>>>(obsb, 1024, W1t, 1024, Y, 512, b1, 1024, 0);
  bn_elu_k<<<T_, 512, 0, stream>>>(Y, g1, be1, Xb);
  gemm_bt_k<<<dim3(256, 4), 256, 0, stream>>>(Xb, 512, W2t, 512, Y, 512, b2, 512, 0);
  bn_elu_k<<<T_, 512, 0, stream>>>(Y, g2, be2, Xb);
  gemm_bt_k<<<dim3(256, 2), 256, 0, stream>>>(Xb, 512, W3t, 512, Yg, 256, b3, 512, 0);
  cast_k<<<MT_ * 256 / 256, 256, 0, stream>>>(Yg, XG, (long)MT_ * 256);

  // per-step constants: Penc -> C0[:,0:256); r/z pre -> C0[:,256:768); hn0 -> C0[:,768:1024); INN
  penc_k<<<MT_, 256, 0, stream>>>(AE, Whe, bhe, C0, Pencb);
  gemm_bt_k<<<dim3(256, 4), 256, 0, stream>>>(XG, 256, Wiht, 256, C0 + 256, 1024, bsum, 256, 0);
  gemm_bt_k<<<dim3(256, 4), 256, 0, stream>>>(Pencb, 256, Whht, 256, C0 + 256, 1024, nullptr, 256, 1);
  gemm_bt_k<<<dim3(256, 2), 256, 0, stream>>>(Pencb, 256, Whht + 512 * 256, 256, C0 + 768, 1024, bhh + 512, 256, 0);
  gemm_bt_k<<<dim3(256, 2), 256, 0, stream>>>(XG, 256, Wiht + 512 * 256, 256, INN, 256, bih + 512, 256, 0);

  // sequential recurrence: 16 independent blocks, each owns 16 batch rows for
  // all 128 steps; h stays in LDS; no inter-block sync of any kind.
  gru_rows_k<<<16, 1024, 0, stream>>>(Wct, C0, INN, outF);
}

// Round 9
// 1202.183 us; speedup vs baseline: 1.2139x; 1.2139x over previous
//
#include <hip/hip_runtime.h>
#include <math.h>
#include <stdint.h>

// Problem constants
#define B_   256
#define T_   128
#define NIN_ 1024
#define H1_  512
#define E_   256
#define A_   16
#define MT_  (B_ * T_)   // 32768 rows, t-major: m = t*B_ + b

typedef unsigned short ushort_t;
typedef __attribute__((ext_vector_type(8))) short   short8;
typedef __attribute__((ext_vector_type(8))) __bf16  bf16x8;
typedef __attribute__((ext_vector_type(4))) float   f32x4;

union frag8 { short8 s; bf16x8 b; };

__device__ __forceinline__ ushort_t f2bf(float f) {
  union { float f; unsigned u; } v; v.f = f;
  unsigned r = (v.u + 0x7FFFu + ((v.u >> 16) & 1u)) >> 16;   // RNE
  return (ushort_t)r;
}

// ---------------- workspace layout (bytes) ----------------
// C0 fp32 [T*B][1024] = 128MB at 0 (written late; obs_b bf16 64MB overlays it early)
// chunks of C0 row: [0:256)=Penc(h_enc init) [256:512)=r_pre0 [512:768)=z_pre0 [768:1024)=hn0
static constexpr size_t OFF_C0    = 0;
static constexpr size_t OFF_OBSB  = 0;                      // bf16 [32768][1024], dead after G1
static constexpr size_t OFF_Y     = 134217728;              // fp32 [32768][512] (Y1,Y2)
static constexpr size_t OFF_YG    = 134217728;              // fp32 [32768][256] (after Y2 dead)
static constexpr size_t OFF_XG    = 167772160;              // bf16 [32768][256]
static constexpr size_t OFF_PENCB = 184549376;              // bf16 [32768][256] (after BN2)
static constexpr size_t OFF_XB    = 201326592;              // bf16 [32768][512] (X1,X2)
static constexpr size_t OFF_INN   = 201326592;              // fp32 [32768][256] (after XB dead)
static constexpr size_t OFF_AE    = 234881024;              // fp32 [32768][16]
static constexpr size_t OFF_W1T   = 236978176;              // bf16 [512][1024]
static constexpr size_t OFF_W2T   = 238026752;              // bf16 [512][512]
static constexpr size_t OFF_W3T   = 238551040;              // bf16 [256][512]
static constexpr size_t OFF_WIHT  = 239075328;              // bf16 [768][256]
static constexpr size_t OFF_WHHT  = 239468544;              // bf16 [768][256]
static constexpr size_t OFF_WCT   = 240123904;              // bf16 [1024][256]  (combined W^T)
static constexpr size_t OFF_BSUM  = 241172480;              // fp32 [768]
static constexpr size_t OFF_FLAGS = 241176576;              // u32 [16] spaced 128B
static constexpr size_t OFF_HG    = 241238016;              // u32 [2][256][128] (bf16x2 h slices)

// ---------------- prologue kernels ----------------

// obs [B,T,NIN] fp32 -> obs_b bf16 t-major [t*B+b][NIN]
__global__ __launch_bounds__(256) void cast_obs_k(const float* __restrict__ obs,
                                                  ushort_t* __restrict__ out) {
  int row_in = blockIdx.x;              // b*T + t
  int b = row_in / T_, t = row_in - b * T_;
  const float4* s4 = (const float4*)(obs + (size_t)row_in * NIN_);
  float4 v = s4[threadIdx.x];
  ushort_t* d = out + (size_t)(t * B_ + b) * NIN_ + threadIdx.x * 4;
  d[0] = f2bf(v.x); d[1] = f2bf(v.y); d[2] = f2bf(v.z); d[3] = f2bf(v.w);
}

// generic fp32 [R,C] -> bf16 [C,R] transpose+cast
__global__ __launch_bounds__(256) void transpose_cast_k(const float* __restrict__ in,
                                                        ushort_t* __restrict__ out,
                                                        int R, int C) {
  __shared__ float tile[32][33];
  int c0 = blockIdx.x * 32, r0 = blockIdx.y * 32;
  int tx = threadIdx.x & 31, ty = threadIdx.x >> 5;   // ty 0..7
  for (int i = 0; i < 4; i++) {
    int r = r0 + ty * 4 + i;
    if (r < R && (c0 + tx) < C) tile[ty * 4 + i][tx] = in[(size_t)r * C + c0 + tx];
  }
  __syncthreads();
  for (int i = 0; i < 4; i++) {
    int c = c0 + ty * 4 + i, r = r0 + tx;
    if (c < C && r < R) out[(size_t)c * R + r] = f2bf(tile[tx][ty * 4 + i]);
  }
}

// Wct rows 0..255: (Whe_h)^T  : Wct[c][k] = Whe[k][c]
__global__ __launch_bounds__(256) void wct_a_k(const float* __restrict__ Whe,
                                               ushort_t* __restrict__ Wct) {
  int c = blockIdx.x, k = threadIdx.x;
  Wct[(size_t)c * 256 + k] = f2bf(Whe[(size_t)k * 256 + c]);
}

// Wct rows 256..1023: (Whe_h @ Whh)^T computed in fp32, one bf16 rounding
__global__ __launch_bounds__(256) void wct_b_k(const float* __restrict__ Whe,
                                               const float* __restrict__ Whh,
                                               ushort_t* __restrict__ Wct) {
  int c = blockIdx.x;   // 0..767 (gh column)
  int k = threadIdx.x;  // h feature
  float acc = 0.f;
  for (int j = 0; j < 256; j++)
    acc += Whe[(size_t)k * 256 + j] * Whh[(size_t)j * 768 + c];
  Wct[(size_t)(256 + c) * 256 + k] = f2bf(acc);
}

__global__ void bsum_k(const float* __restrict__ bih, const float* __restrict__ bhh,
                       float* __restrict__ bs) {
  int i = blockIdx.x * 256 + threadIdx.x;
  if (i < 768) bs[i] = bih[i] + bhh[i];
}

__global__ void init_flags_k(unsigned* f) {
  if (threadIdx.x < 16) f[threadIdx.x * 32] = 0u;
}

// AE[m=t*B+b][k2] = actions[b,t,:] @ Wae + bae   (fp32)
__global__ __launch_bounds__(256) void ae_k(const float* __restrict__ actions,
                                            const float* __restrict__ Wae,
                                            const float* __restrict__ bae,
                                            float* __restrict__ AE) {
  int idx = blockIdx.x * 256 + threadIdx.x;
  int m = idx >> 4, k2 = idx & 15;
  int t = m >> 8, b = m & 255;
  const float* arow = actions + ((size_t)b * T_ + t) * A_;
  float acc = bae[k2];
  for (int k = 0; k < 16; k++) acc += arow[k] * Wae[k * 16 + k2];
  AE[(size_t)m * 16 + k2] = acc;
}

// Penc[t][b][j] = bhe[j] + (t>0 ? AE[t-1,b,:] @ Whe[256:272,:] : 0)
// writes fp32 into C0 cols [0:256) and bf16 copy to Pencb
__global__ __launch_bounds__(256) void penc_k(const float* __restrict__ AE,
                                              const float* __restrict__ Whe,
                                              const float* __restrict__ bhe,
                                              float* __restrict__ C0,
                                              ushort_t* __restrict__ Pencb) {
  int m = blockIdx.x;          // t*B + b
  int j = threadIdx.x;         // 0..255
  __shared__ float a[16];
  if (threadIdx.x < 16)
    a[threadIdx.x] = (m >= B_) ? AE[(size_t)(m - B_) * 16 + threadIdx.x] : 0.f;
  __syncthreads();
  float acc = bhe[j];
  if (m >= B_) {
    for (int k = 0; k < 16; k++) acc += a[k] * Whe[(size_t)(256 + k) * 256 + j];
  }
  C0[(size_t)m * 1024 + j] = acc;
  Pencb[(size_t)m * 256 + j] = f2bf(acc);
}

// per-t BatchNorm (training, biased var) + ELU, fp32 in -> bf16 out
__global__ __launch_bounds__(512) void bn_elu_k(const float* __restrict__ Y,
                                                const float* __restrict__ g,
                                                const float* __restrict__ be,
                                                ushort_t* __restrict__ Xb) {
  int t = blockIdx.x, f = threadIdx.x;   // 512 features
  const float* base = Y + (size_t)t * B_ * H1_;
  float s = 0.f, ss = 0.f;
  for (int b = 0; b < B_; b++) {
    float v = base[(size_t)b * H1_ + f];
    s += v; ss += v * v;
  }
  float mu  = s * (1.f / B_);
  float var = ss * (1.f / B_) - mu * mu;
  float inv = 1.f / sqrtf(var + 1e-5f);
  float sc = g[f] * inv, sh = be[f] - mu * sc;
  ushort_t* ob = Xb + (size_t)t * B_ * H1_;
  for (int b = 0; b < B_; b++) {
    float v = base[(size_t)b * H1_ + f] * sc + sh;
    float e = v > 0.f ? v : (expf(v) - 1.f);
    ob[(size_t)b * H1_ + f] = f2bf(e);
  }
}

__global__ __launch_bounds__(256) void cast_k(const float* __restrict__ in,
                                              ushort_t* __restrict__ out, long n) {
  long i = (long)blockIdx.x * 256 + threadIdx.x;
  if (i < n) out[i] = f2bf(in[i]);
}

// ---------------- bf16 MFMA GEMM: C[m,n] (+)= A[m,:] . Bt[n,:] + bias[n] ----------------
// 128x128 tile, BK=32, 256 threads (4 waves in 2x2, each 64x64, 4x4 frag grid).
__global__ __launch_bounds__(256) void gemm_bt_k(const ushort_t* __restrict__ A, int lda,
                                                 const ushort_t* __restrict__ Bt, int ldb,
                                                 float* __restrict__ C, int ldc,
                                                 const float* __restrict__ bias,
                                                 int K, int accum) {
  __shared__ __align__(16) ushort_t As[128][40];
  __shared__ __align__(16) ushort_t Bs[128][40];
  int tid = threadIdx.x;
  int wave = tid >> 6, lane = tid & 63;
  int q = lane >> 4, l15 = lane & 15;
  int wr = wave >> 1, wc = wave & 1;
  int m0 = blockIdx.x * 128, n0 = blockIdx.y * 128;
  f32x4 acc[4][4] = {};
  int r = tid >> 1, sh = (tid & 1) * 16;
  const ushort_t* aSrc = A + (size_t)(m0 + r) * lda + sh;
  const ushort_t* bSrc = Bt + (size_t)(n0 + r) * ldb + sh;
  for (int k0 = 0; k0 < K; k0 += 32) {
    *(short8*)&As[r][sh]     = *(const short8*)(aSrc + k0);
    *(short8*)&As[r][sh + 8] = *(const short8*)(aSrc + k0 + 8);
    *(short8*)&Bs[r][sh]     = *(const short8*)(bSrc + k0);
    *(short8*)&Bs[r][sh + 8] = *(const short8*)(bSrc + k0 + 8);
    __syncthreads();
    frag8 af[4], bf[4];
#pragma unroll
    for (int i = 0; i < 4; i++) {
      af[i].s = *(const short8*)&As[wr * 64 + i * 16 + l15][q * 8];
      bf[i].s = *(const short8*)&Bs[wc * 64 + i * 16 + l15][q * 8];
    }
#pragma unroll
    for (int at = 0; at < 4; at++)
#pragma unroll
      for (int bt = 0; bt < 4; bt++)
        acc[at][bt] = __builtin_amdgcn_mfma_f32_16x16x32_bf16(af[at].b, bf[bt].b, acc[at][bt], 0, 0, 0);
    __syncthreads();
  }
#pragma unroll
  for (int at = 0; at < 4; at++)
#pragma unroll
    for (int bt = 0; bt < 4; bt++) {
      int mb = m0 + wr * 64 + at * 16 + q * 4;
      int n  = n0 + wc * 64 + bt * 16 + l15;
      float bv = bias ? bias[n] : 0.f;
#pragma unroll
      for (int i = 0; i < 4; i++) {
        size_t idx = (size_t)(mb + i) * ldc + n;
        float v = acc[at][bt][i] + bv;
        if (accum) v += C[idx];
        C[idx] = v;
      }
    }
}

// ---------------- GRU recurrence v6: column-partition, LDS-resident weights ----
// 64 blocks = 16 rg x 4 cg. Block (rg,cg) owns batch rows [16rg,16rg+16) and
// h-cols [64cg,64cg+64) -- ALL 4 gates for those cols, weight slice = 128KB
// in LDS (allocator-proof residency). Per-CU streamed bytes/step: 20KB C0/INN
// (vs 464KB in v5) -> stream floor gone; new costs are LDS-fed MFMA (~2.3k cy)
// + h-exchange.
// h-exchange without global barrier: h slices double-buffered in global (hG),
// written/read as AGENT-scope ATOMIC u32 (bf16x2) -- coherent via IC, no L2
// invalidate needed (and weights are in LDS, immune to cache ops). Sync: one
// monotone u32 counter per rg; 4 producers release-increment after writing
// h(t+1); consumers acquire-spin for 4t before reading h(t). Double-buffering
// makes write-after-read safe; counters never reset -> no deadlock.
// 16 waves/block: wave w -> gate g=w>>2, col-tile j=w&3 (cols 16j..16j+16).
// Gate mixing crosses waves -> exchange pre-activations through LDS G[].
__global__ __launch_bounds__(1024) void gru_cols_k(
    const ushort_t* __restrict__ Wct,
    const float* __restrict__ C0,
    const float* __restrict__ INN,
    unsigned* __restrict__ hG,        // [2][256][128] u32 (bf16x2)
    unsigned* __restrict__ flags,     // [16] spaced 32 u32
    float* __restrict__ outF) {
  __shared__ __align__(16) ushort_t Wb[256][264];   // weight slice (135.2KB)
  __shared__ __align__(16) ushort_t h_lds[16][264]; // h(t), full 256 k (8.4KB)
  __shared__ float G[4][16][66];                    // gate pre-acts (16.9KB)

  const int tid = threadIdx.x;
  const int w = tid >> 6, lane = tid & 63;
  const int q = lane >> 4, l15 = lane & 15;
  const int rg = blockIdx.x & 15, cg = blockIdx.x >> 4;
  const int r0 = rg * 16;
  const int g = w >> 2, j = w & 3;

  unsigned* flag = flags + rg * 32;

  // zero h(0) incl. pad
  for (int d = tid; d < 16 * 264 / 2; d += 1024) ((unsigned*)h_lds)[d] = 0u;
  // stage weight slice: Wb[g*64+lc][k] = Wct[g*256 + cg*64 + lc][k]
  for (int i = tid; i < 256 * 32; i += 1024) {
    int rr = i >> 5, ss = i & 31;
    int srow = (rr >> 6) * 256 + cg * 64 + (rr & 63);
    *(short8*)&Wb[rr][ss * 8] = *(const short8*)(Wct + (size_t)srow * 256 + ss * 8);
  }
  __syncthreads();

  const int crow = tid >> 6;        // combine row 0..15
  const int ccol = tid & 63;        // combine local col 0..63
  const int hg = cg * 64 + ccol;    // global h-col

  for (int t = 0; t < T_; t++) {
    // prefetch C0/INN for combine (independent of h -> in flight during spin)
    const float* c0t  = C0  + ((size_t)t * B_ + r0) * 1024;
    const float* innt = INN + ((size_t)t * B_ + r0) * 256;
    float c0he = c0t[(size_t)crow * 1024 + hg];
    float c0r  = c0t[(size_t)crow * 1024 + 256 + hg];
    float c0z  = c0t[(size_t)crow * 1024 + 512 + hg];
    float c0hn = c0t[(size_t)crow * 1024 + 768 + hg];
    float c0in = innt[(size_t)crow * 256 + hg];

    if (t > 0) {
      // wait for all 4 cg-blocks of this rg to have published h(t)
      if (tid == 0) {
        unsigned target = 4u * (unsigned)t;
        while (__hip_atomic_load(flag, __ATOMIC_ACQUIRE, __HIP_MEMORY_SCOPE_AGENT) < target)
          __builtin_amdgcn_s_sleep(1);
      }
      __syncthreads();
      // pull the 3 remote slices (coherent atomic loads -> no stale L1/L2)
      const unsigned* hsrc = hG + (size_t)(t & 1) * 256 * 128;
      for (int d = tid; d < 1536; d += 1024) {
        int s = d >> 9;
        int cgs = s + (s >= cg ? 1 : 0);
        int row = (d >> 5) & 15, cp = d & 31;
        unsigned v = __hip_atomic_load(&hsrc[(size_t)(r0 + row) * 128 + cgs * 32 + cp],
                                       __ATOMIC_RELAXED, __HIP_MEMORY_SCOPE_AGENT);
        *(unsigned*)&h_lds[row][cgs * 64 + cp * 2] = v;
      }
      __syncthreads();
    }

    // MFMA: wave (g,j) computes gate g, cols [16j,16j+16), rows 16, k=256
    f32x4 acc = {};
#pragma unroll
    for (int kc = 0; kc < 8; kc++) {
      frag8 a, b;
      a.s = *(const short8*)&h_lds[l15][kc * 32 + q * 8];
      b.s = *(const short8*)&Wb[g * 64 + j * 16 + l15][kc * 32 + q * 8];
      acc = __builtin_amdgcn_mfma_f32_16x16x32_bf16(a.b, b.b, acc, 0, 0, 0);
    }
#pragma unroll
    for (int i = 0; i < 4; i++) G[g][q * 4 + i][j * 16 + l15] = acc[i];
    __syncthreads();

    // combine: thread (crow, ccol) mixes the 4 gates for its h element
    float henc = G[0][crow][ccol] + c0he;
    float rp   = G[1][crow][ccol] + c0r;
    float zp   = G[2][crow][ccol] + c0z;
    float hn   = G[3][crow][ccol] + c0hn;
    float rgate = 1.f / (1.f + expf(-rp));
    float zgate = 1.f / (1.f + expf(-zp));
    float ng = tanhf(c0in + rgate * hn);
    float hv = (1.f - zgate) * ng + zgate * henc;

    if (t < T_ - 1) {
      h_lds[crow][cg * 64 + ccol] = f2bf(hv);   // own slice, local
      __syncthreads();
      // publish own slice as coherent bf16x2 stores
      if (tid < 512) {
        int row2 = tid >> 5, cp = tid & 31;
        unsigned v = *(const unsigned*)&h_lds[row2][cg * 64 + cp * 2];
        unsigned* hdst = hG + (size_t)((t + 1) & 1) * 256 * 128;
        __hip_atomic_store(&hdst[(size_t)(r0 + row2) * 128 + cg * 32 + cp], v,
                           __ATOMIC_RELAXED, __HIP_MEMORY_SCOPE_AGENT);
      }
      __syncthreads();                          // drains vmcnt -> stores done
      if (tid == 0)
        __hip_atomic_fetch_add(flag, 1u, __ATOMIC_RELEASE, __HIP_MEMORY_SCOPE_AGENT);
    } else {
      outF[(size_t)(r0 + crow) * 256 + hg] = hv;
    }
  }
}

// ---------------- launch ----------------
extern "C" void kernel_launch(void* const* d_in, const int* in_sizes, int n_in,
                              void* d_out, int out_size, void* d_ws, size_t ws_size,
                              hipStream_t stream) {
  const float* obs     = (const float*)d_in[0];
  const float* actions = (const float*)d_in[1];
  const float* W1  = (const float*)d_in[2];
  const float* b1  = (const float*)d_in[3];
  const float* g1  = (const float*)d_in[4];
  const float* be1 = (const float*)d_in[5];
  const float* W2  = (const float*)d_in[6];
  const float* b2  = (const float*)d_in[7];
  const float* g2  = (const float*)d_in[8];
  const float* be2 = (const float*)d_in[9];
  const float* W3  = (const float*)d_in[10];
  const float* b3  = (const float*)d_in[11];
  const float* Wih = (const float*)d_in[12];
  const float* bih = (const float*)d_in[13];
  const float* Whh = (const float*)d_in[14];
  const float* bhh = (const float*)d_in[15];
  const float* Whe = (const float*)d_in[16];
  const float* bhe = (const float*)d_in[17];
  const float* Wae = (const float*)d_in[18];
  const float* bae = (const float*)d_in[19];

  char* ws = (char*)d_ws;
  float*    C0    = (float*)(ws + OFF_C0);
  ushort_t* obsb  = (ushort_t*)(ws + OFF_OBSB);
  float*    Y     = (float*)(ws + OFF_Y);
  float*    Yg    = (float*)(ws + OFF_YG);
  ushort_t* XG    = (ushort_t*)(ws + OFF_XG);
  ushort_t* Pencb = (ushort_t*)(ws + OFF_PENCB);
  ushort_t* Xb    = (ushort_t*)(ws + OFF_XB);
  float*    INN   = (float*)(ws + OFF_INN);
  float*    AE    = (float*)(ws + OFF_AE);
  ushort_t* W1t   = (ushort_t*)(ws + OFF_W1T);
  ushort_t* W2t   = (ushort_t*)(ws + OFF_W2T);
  ushort_t* W3t   = (ushort_t*)(ws + OFF_W3T);
  ushort_t* Wiht  = (ushort_t*)(ws + OFF_WIHT);
  ushort_t* Whht  = (ushort_t*)(ws + OFF_WHHT);
  ushort_t* Wct   = (ushort_t*)(ws + OFF_WCT);
  float*    bsum  = (float*)(ws + OFF_BSUM);
  unsigned* flags = (unsigned*)(ws + OFF_FLAGS);
  unsigned* hG    = (unsigned*)(ws + OFF_HG);
  float*    outF  = (float*)d_out;

  // prologue: casts / transposes / small precomputes
  cast_obs_k<<<MT_, 256, 0, stream>>>(obs, obsb);
  transpose_cast_k<<<dim3(16, 32), 256, 0, stream>>>(W1, W1t, 1024, 512);
  transpose_cast_k<<<dim3(16, 16), 256, 0, stream>>>(W2, W2t, 512, 512);
  transpose_cast_k<<<dim3(8, 16),  256, 0, stream>>>(W3, W3t, 512, 256);
  transpose_cast_k<<<dim3(24, 8),  256, 0, stream>>>(Wih, Wiht, 256, 768);
  transpose_cast_k<<<dim3(24, 8),  256, 0, stream>>>(Whh, Whht, 256, 768);
  wct_a_k<<<256, 256, 0, stream>>>(Whe, Wct);
  wct_b_k<<<768, 256, 0, stream>>>(Whe, Whh, Wct);
  bsum_k<<<3, 256, 0, stream>>>(bih, bhh, bsum);
  init_flags_k<<<1, 64, 0, stream>>>(flags);
  ae_k<<<MT_ * 16 / 256, 256, 0, stream>>>(actions, Wae, bae, AE);

  // MLP (parallel over all T*B rows, t-major) -- 128x128 tiles
  gemm_bt_k<<<dim3(256, 4), 256, 0, stream>>>(obsb, 1024, W1t, 1024, Y, 512, b1, 1024, 0);
  bn_elu_k<<<T_, 512, 0, stream>>>(Y, g1, be1, Xb);
  gemm_bt_k<<<dim3(256, 4), 256, 0, stream>>>(Xb, 512, W2t, 512, Y, 512, b2, 512, 0);
  bn_elu_k<<<T_, 512, 0, stream>>>(Y, g2, be2, Xb);
  gemm_bt_k<<<dim3(256, 2), 256, 0, stream>>>(Xb, 512, W3t, 512, Yg, 256, b3, 512, 0);
  cast_k<<<MT_ * 256 / 256, 256, 0, stream>>>(Yg, XG, (long)MT_ * 256);

  // per-step constants: Penc -> C0[:,0:256); r/z pre -> C0[:,256:768); hn0 -> C0[:,768:1024); INN
  penc_k<<<MT_, 256, 0, stream>>>(AE, Whe, bhe, C0, Pencb);
  gemm_bt_k<<<dim3(256, 4), 256, 0, stream>>>(XG, 256, Wiht, 256, C0 + 256, 1024, bsum, 256, 0);
  gemm_bt_k<<<dim3(256, 4), 256, 0, stream>>>(Pencb, 256, Whht, 256, C0 + 256, 1024, nullptr, 256, 1);
  gemm_bt_k<<<dim3(256, 2), 256, 0, stream>>>(Pencb, 256, Whht + 512 * 256, 256, C0 + 768, 1024, bhh + 512, 256, 0);
  gemm_bt_k<<<dim3(256, 2), 256, 0, stream>>>(XG, 256, Wiht + 512 * 256, 256, INN, 256, bih + 512, 256, 0);

  // recurrence: 64 blocks (16 rg x 4 cg), LDS-resident weight slices,
  // flag-synced h-exchange through the IC (no global barrier).
  gru_cols_k<<<64, 1024, 0, stream>>>(Wct, C0, INN, hG, flags, outF);
}